// Round 1
// baseline (585.192 us; speedup 1.0000x reference)
//
#include <hip/hip_runtime.h>
#include <hip/hip_bf16.h>
#include <stdint.h>

#define B_    4
#define S_    2048
#define D_    1024
#define H_    16
#define DH_   64
#define M_TOT 8192      // B*S
#define NQKV  3072      // 3*H*DH
#define HDH   1024      // H*DH

typedef __bf16 bf16_t;
typedef bf16_t bf16x8 __attribute__((ext_vector_type(8)));
typedef float  f32x4  __attribute__((ext_vector_type(4)));

__device__ __forceinline__ short f2bf(float f) {
  union { float f; uint32_t u; } x; x.f = f;
  uint32_t r = (x.u + 0x7fffu + ((x.u >> 16) & 1u)) >> 16;
  return (short)(uint16_t)r;
}

#define ASYNC_COPY16(g, l) \
  __builtin_amdgcn_global_load_lds((const __attribute__((address_space(1))) void*)(g), \
                                   (__attribute__((address_space(3))) void*)(l), 16, 0, 0)

// ---------------- prep kernels ----------------

__global__ __launch_bounds__(256) void k_cvt(const float* __restrict__ in, short* __restrict__ out, int n4) {
  int i = blockIdx.x * 256 + threadIdx.x;
  if (i < n4) {
    float4 v = ((const float4*)in)[i];
    short4 o;
    o.x = f2bf(v.x); o.y = f2bf(v.y); o.z = f2bf(v.z); o.w = f2bf(v.w);
    ((short4*)out)[i] = o;
  }
}

// in: (R,C) f32 row-major -> out: (C,R) bf16 row-major
__global__ __launch_bounds__(256) void k_transpose(const float* __restrict__ in, short* __restrict__ out, int R, int C) {
  int idx = blockIdx.x * 256 + threadIdx.x;
  if (idx < R * C) {
    int r = idx / C, c = idx % C;
    out[(size_t)c * R + r] = f2bf(in[idx]);
  }
}

// ---------------- GEMM core: C = A(row-major MxK) * Bt(row-major NxK)^T ----------------

__device__ __forceinline__ void gemm_core(const short* __restrict__ A,
                                          const short* __restrict__ Bt,
                                          int row0, int col0, int K,
                                          short* lA, short* lB,
                                          f32x4 acc[4][4]) {
  const int tid  = threadIdx.x;
  const int wave = tid >> 6, lane = tid & 63;
  const int wr = wave >> 1, wc = wave & 1;
  const int stg_r = lane >> 2;         // 0..15
  const int stg_k = (lane & 3) * 8;    // 0,8,16,24
  const int fr = lane & 15;
  const int fk = (lane >> 4) * 8;

  for (int k0 = 0; k0 < K; k0 += 32) {
    __syncthreads();
#pragma unroll
    for (int c = 0; c < 2; ++c) {
      const int seg = wave * 2 + c;    // 0..7
      const short* ga = A  + (size_t)(row0 + seg * 16 + stg_r) * K + (k0 + stg_k);
      const short* gb = Bt + (size_t)(col0 + seg * 16 + stg_r) * K + (k0 + stg_k);
      ASYNC_COPY16(ga, lA + seg * 512);
      ASYNC_COPY16(gb, lB + seg * 512);
    }
    __syncthreads();
    bf16x8 af[4], bfr[4];
#pragma unroll
    for (int m = 0; m < 4; ++m)
      af[m] = *(const bf16x8*)(lA + (wr * 64 + m * 16 + fr) * 32 + fk);
#pragma unroll
    for (int n = 0; n < 4; ++n)
      bfr[n] = *(const bf16x8*)(lB + (wc * 64 + n * 16 + fr) * 32 + fk);
#pragma unroll
    for (int m = 0; m < 4; ++m)
#pragma unroll
      for (int n = 0; n < 4; ++n)
        acc[m][n] = __builtin_amdgcn_mfma_f32_16x16x32_bf16(af[m], bfr[n], acc[m][n], 0, 0, 0);
  }
}

// QKV GEMM: A = x_bf16 (8192x1024), Bt = wqkvT (3072x1024). Epilogue scatters
// to Q (B,H,S,DH), K (B,H,S,DH), Vt (B,H,DH,S) with bias add.
__global__ __launch_bounds__(256) void k_gemm_qkv(const short* __restrict__ A, const short* __restrict__ Bt,
                                                  const float* __restrict__ bias,
                                                  short* __restrict__ Qb, short* __restrict__ Kb,
                                                  short* __restrict__ Vt) {
  __shared__ short lA[128 * 32];
  __shared__ short lB[128 * 32];
  f32x4 acc[4][4];
#pragma unroll
  for (int m = 0; m < 4; ++m)
#pragma unroll
    for (int n = 0; n < 4; ++n)
      acc[m][n] = (f32x4){0.f, 0.f, 0.f, 0.f};
  const int row0 = blockIdx.x * 128, col0 = blockIdx.y * 128;
  gemm_core(A, Bt, row0, col0, D_, lA, lB, acc);
  const int lane = threadIdx.x & 63, wave = threadIdx.x >> 6;
  const int wr = wave >> 1, wc = wave & 1;
#pragma unroll
  for (int m = 0; m < 4; ++m) {
    const int rbase = row0 + wr * 64 + m * 16 + (lane >> 4) * 4;
#pragma unroll
    for (int n = 0; n < 4; ++n) {
      const int col = col0 + wc * 64 + n * 16 + (lane & 15);
      const float bv = bias[col];
      const int t = col >> 10, rem = col & 1023, hh = rem >> 6, e = rem & 63;
#pragma unroll
      for (int r = 0; r < 4; ++r) {
        const int rw = rbase + r;
        const int bb = rw >> 11, s = rw & 2047;
        const short o = f2bf(acc[m][n][r] + bv);
        if (t == 0)      Qb[((size_t)(bb * H_ + hh) * S_ + s) * DH_ + e] = o;
        else if (t == 1) Kb[((size_t)(bb * H_ + hh) * S_ + s) * DH_ + e] = o;
        else             Vt[((size_t)(bb * H_ + hh) * DH_ + e) * S_ + s] = o;
      }
    }
  }
}

// Output GEMM: A = att (8192x1024), Bt = woutT (1024x1024), C = out f32 + bias.
__global__ __launch_bounds__(256) void k_gemm_out(const short* __restrict__ A, const short* __restrict__ Bt,
                                                  const float* __restrict__ bias, float* __restrict__ C) {
  __shared__ short lA[128 * 32];
  __shared__ short lB[128 * 32];
  f32x4 acc[4][4];
#pragma unroll
  for (int m = 0; m < 4; ++m)
#pragma unroll
    for (int n = 0; n < 4; ++n)
      acc[m][n] = (f32x4){0.f, 0.f, 0.f, 0.f};
  const int row0 = blockIdx.x * 128, col0 = blockIdx.y * 128;
  gemm_core(A, Bt, row0, col0, HDH, lA, lB, acc);
  const int lane = threadIdx.x & 63, wave = threadIdx.x >> 6;
  const int wr = wave >> 1, wc = wave & 1;
#pragma unroll
  for (int m = 0; m < 4; ++m) {
    const int rbase = row0 + wr * 64 + m * 16 + (lane >> 4) * 4;
#pragma unroll
    for (int n = 0; n < 4; ++n) {
      const int col = col0 + wc * 64 + n * 16 + (lane & 15);
      const float bv = bias[col];
#pragma unroll
      for (int r = 0; r < 4; ++r)
        C[(size_t)(rbase + r) * D_ + col] = acc[m][n][r] + bv;
    }
  }
}

// ---------------- flash attention (causal) ----------------
// grid (S/64, H, B), 256 threads = 4 waves; each wave owns 16 q-rows independently.
__global__ __launch_bounds__(256) void k_attn(const short* __restrict__ Qb, const short* __restrict__ Kb,
                                              const short* __restrict__ Vt, short* __restrict__ att) {
  __shared__ short pl[4][16 * 32];
  const int qt = blockIdx.x, h = blockIdx.y, b = blockIdx.z;
  const int wave = threadIdx.x >> 6, lane = threadIdx.x & 63;
  const int q0 = qt * 64 + wave * 16;
  const size_t bh = (size_t)(b * H_ + h);
  const short* Qp = Qb + bh * S_ * DH_;
  const short* Kp = Kb + bh * S_ * DH_;
  const short* Vp = Vt + bh * DH_ * S_;
  const int fr = lane & 15, fg = lane >> 4;

  bf16x8 qf[2];
#pragma unroll
  for (int kb = 0; kb < 2; ++kb)
    qf[kb] = *(const bf16x8*)(Qp + (q0 + fr) * DH_ + kb * 32 + fg * 8);

  f32x4 oacc[4];
#pragma unroll
  for (int n = 0; n < 4; ++n) oacc[n] = (f32x4){0.f, 0.f, 0.f, 0.f};
  float mrow[4], lrow[4];
#pragma unroll
  for (int r = 0; r < 4; ++r) { mrow[r] = -1e38f; lrow[r] = 0.f; }

  const int kend = q0 + 16;
  for (int kt = 0; kt < kend; kt += 32) {
    f32x4 sc[2];
    sc[0] = (f32x4){0.f, 0.f, 0.f, 0.f};
    sc[1] = (f32x4){0.f, 0.f, 0.f, 0.f};
#pragma unroll
    for (int nt = 0; nt < 2; ++nt)
#pragma unroll
      for (int kb = 0; kb < 2; ++kb) {
        bf16x8 kf = *(const bf16x8*)(Kp + (kt + nt * 16 + fr) * DH_ + kb * 32 + fg * 8);
        sc[nt] = __builtin_amdgcn_mfma_f32_16x16x32_bf16(qf[kb], kf, sc[nt], 0, 0, 0);
      }
    float sv[2][4];
#pragma unroll
    for (int nt = 0; nt < 2; ++nt)
#pragma unroll
      for (int r = 0; r < 4; ++r) {
        const int qi = q0 + fg * 4 + r;
        const int ki = kt + nt * 16 + fr;
        float v = sc[nt][r] * 0.125f;
        sv[nt][r] = (ki <= qi) ? v : -1e30f;
      }
    float pm[4];
#pragma unroll
    for (int r = 0; r < 4; ++r) pm[r] = fmaxf(sv[0][r], sv[1][r]);
#pragma unroll
    for (int off = 1; off < 16; off <<= 1)
#pragma unroll
      for (int r = 0; r < 4; ++r) pm[r] = fmaxf(pm[r], __shfl_xor(pm[r], off, 64));
    float mnew[4], scl[4];
#pragma unroll
    for (int r = 0; r < 4; ++r) {
      mnew[r] = fmaxf(mrow[r], pm[r]);
      scl[r] = __expf(mrow[r] - mnew[r]);
      mrow[r] = mnew[r];
    }
    float pv[2][4], ps[4];
#pragma unroll
    for (int r = 0; r < 4; ++r) ps[r] = 0.f;
#pragma unroll
    for (int nt = 0; nt < 2; ++nt)
#pragma unroll
      for (int r = 0; r < 4; ++r) {
        pv[nt][r] = __expf(sv[nt][r] - mnew[r]);
        ps[r] += pv[nt][r];
      }
#pragma unroll
    for (int off = 1; off < 16; off <<= 1)
#pragma unroll
      for (int r = 0; r < 4; ++r) ps[r] += __shfl_xor(ps[r], off, 64);
#pragma unroll
    for (int r = 0; r < 4; ++r) lrow[r] = lrow[r] * scl[r] + ps[r];
#pragma unroll
    for (int n = 0; n < 4; ++n)
#pragma unroll
      for (int r = 0; r < 4; ++r) oacc[n][r] *= scl[r];

    // P tile (16q x 32k) -> LDS, reload as MFMA A-fragment
    short* pw = pl[wave];
#pragma unroll
    for (int nt = 0; nt < 2; ++nt)
#pragma unroll
      for (int r = 0; r < 4; ++r)
        pw[(fg * 4 + r) * 32 + nt * 16 + fr] = f2bf(pv[nt][r]);
    bf16x8 pa = *(const bf16x8*)(pw + fr * 32 + fg * 8);
#pragma unroll
    for (int n = 0; n < 4; ++n) {
      bf16x8 vf = *(const bf16x8*)(Vp + (size_t)(n * 16 + fr) * S_ + kt + fg * 8);
      oacc[n] = __builtin_amdgcn_mfma_f32_16x16x32_bf16(pa, vf, oacc[n], 0, 0, 0);
    }
  }

#pragma unroll
  for (int n = 0; n < 4; ++n)
#pragma unroll
    for (int r = 0; r < 4; ++r) {
      const int qrow = q0 + fg * 4 + r;
      const float v = oacc[n][r] / lrow[r];
      att[(size_t)(b * S_ + qrow) * HDH + h * DH_ + n * 16 + fr] = f2bf(v);
    }
}

// ---------------- launcher ----------------

extern "C" void kernel_launch(void* const* d_in, const int* in_sizes, int n_in,
                              void* d_out, int out_size, void* d_ws, size_t ws_size,
                              hipStream_t stream) {
  const float* x     = (const float*)d_in[0];
  const float* w_qkv = (const float*)d_in[1];
  const float* b_qkv = (const float*)d_in[2];
  const float* w_out = (const float*)d_in[3];
  const float* b_out = (const float*)d_in[4];
  float* out = (float*)d_out;

  char* p = (char*)d_ws;
  short* xb    = (short*)p; p += (size_t)M_TOT * D_ * 2;
  short* wqkvT = (short*)p; p += (size_t)NQKV * D_ * 2;
  short* woutT = (short*)p; p += (size_t)D_ * HDH * 2;
  short* Qb    = (short*)p; p += (size_t)B_ * H_ * S_ * DH_ * 2;
  short* Kb    = (short*)p; p += (size_t)B_ * H_ * S_ * DH_ * 2;
  short* Vt    = (short*)p; p += (size_t)B_ * H_ * S_ * DH_ * 2;
  short* att   = (short*)p; p += (size_t)M_TOT * HDH * 2;

  k_cvt<<<M_TOT * D_ / 4 / 256, 256, 0, stream>>>(x, xb, M_TOT * D_ / 4);
  k_transpose<<<(D_ * NQKV + 255) / 256, 256, 0, stream>>>(w_qkv, wqkvT, D_, NQKV);
  k_transpose<<<(HDH * D_ + 255) / 256, 256, 0, stream>>>(w_out, woutT, HDH, D_);
  k_gemm_qkv<<<dim3(M_TOT / 128, NQKV / 128), 256, 0, stream>>>(xb, wqkvT, b_qkv, Qb, Kb, Vt);
  k_attn<<<dim3(S_ / 64, H_, B_), 256, 0, stream>>>(Qb, Kb, Vt, att);
  k_gemm_out<<<dim3(M_TOT / 128, D_ / 128), 256, 0, stream>>>(att, woutT, b_out, out);
}

// Round 2
// 261.971 us; speedup vs baseline: 2.2338x; 2.2338x over previous
//
#include <hip/hip_runtime.h>
#include <hip/hip_bf16.h>
#include <stdint.h>

#define B_    4
#define S_    2048
#define D_    1024
#define H_    16
#define DH_   64
#define M_TOT 8192      // B*S
#define NQKV  3072      // 3*H*DH
#define HDH   1024      // H*DH

typedef __bf16 bf16_t;
typedef bf16_t bf16x8 __attribute__((ext_vector_type(8)));
typedef float  f32x4  __attribute__((ext_vector_type(4)));
typedef float  f32x16 __attribute__((ext_vector_type(16)));

// scale folded into Q at QKV epilogue: 1/sqrt(64) * log2(e)
#define QSCALE 0.1803368801111204f

__device__ __forceinline__ short f2bf(float f) {
  union { float f; uint32_t u; } x; x.f = f;
  uint32_t r = (x.u + 0x7fffu + ((x.u >> 16) & 1u)) >> 16;
  return (short)(uint16_t)r;
}

__device__ __forceinline__ uint32_t cvt_pk_bf16(float lo, float hi) {
  uint32_t r;
  asm("v_cvt_pk_bf16_f32 %0, %1, %2" : "=v"(r) : "v"(lo), "v"(hi));
  return r;
}

#define ASYNC_COPY16(g, l) \
  __builtin_amdgcn_global_load_lds((const __attribute__((address_space(1))) void*)(g), \
                                   (__attribute__((address_space(3))) void*)(l), 16, 0, 0)

// ---------------- prep kernels ----------------

__global__ __launch_bounds__(256) void k_cvt(const float* __restrict__ in, short* __restrict__ out, int n4) {
  int i = blockIdx.x * 256 + threadIdx.x;
  if (i < n4) {
    float4 v = ((const float4*)in)[i];
    short4 o;
    o.x = f2bf(v.x); o.y = f2bf(v.y); o.z = f2bf(v.z); o.w = f2bf(v.w);
    ((short4*)out)[i] = o;
  }
}

// in: (R,C) f32 row-major -> out: (C,R) bf16 row-major
__global__ __launch_bounds__(256) void k_transpose(const float* __restrict__ in, short* __restrict__ out, int R, int C) {
  int idx = blockIdx.x * 256 + threadIdx.x;
  if (idx < R * C) {
    int r = idx / C, c = idx % C;
    out[(size_t)c * R + r] = f2bf(in[idx]);
  }
}

// ---------------- GEMM core: C = A(row-major MxK) * Bt(row-major NxK)^T ----------------

__device__ __forceinline__ void gemm_core(const short* __restrict__ A,
                                          const short* __restrict__ Bt,
                                          int row0, int col0, int K,
                                          short* lA, short* lB,
                                          f32x4 acc[4][4]) {
  const int tid  = threadIdx.x;
  const int wave = tid >> 6, lane = tid & 63;
  const int wr = wave >> 1, wc = wave & 1;
  const int stg_r = lane >> 2;         // 0..15
  const int stg_k = (lane & 3) * 8;    // 0,8,16,24
  const int fr = lane & 15;
  const int fk = (lane >> 4) * 8;

  for (int k0 = 0; k0 < K; k0 += 32) {
    __syncthreads();
#pragma unroll
    for (int c = 0; c < 2; ++c) {
      const int seg = wave * 2 + c;    // 0..7
      const short* ga = A  + (size_t)(row0 + seg * 16 + stg_r) * K + (k0 + stg_k);
      const short* gb = Bt + (size_t)(col0 + seg * 16 + stg_r) * K + (k0 + stg_k);
      ASYNC_COPY16(ga, lA + seg * 512);
      ASYNC_COPY16(gb, lB + seg * 512);
    }
    __syncthreads();
    bf16x8 af[4], bfr[4];
#pragma unroll
    for (int m = 0; m < 4; ++m)
      af[m] = *(const bf16x8*)(lA + (wr * 64 + m * 16 + fr) * 32 + fk);
#pragma unroll
    for (int n = 0; n < 4; ++n)
      bfr[n] = *(const bf16x8*)(lB + (wc * 64 + n * 16 + fr) * 32 + fk);
#pragma unroll
    for (int m = 0; m < 4; ++m)
#pragma unroll
      for (int n = 0; n < 4; ++n)
        acc[m][n] = __builtin_amdgcn_mfma_f32_16x16x32_bf16(af[m], bfr[n], acc[m][n], 0, 0, 0);
  }
}

// QKV GEMM: A = x_bf16 (8192x1024), Bt = wqkvT (3072x1024). Epilogue scatters
// to Q (B,H,S,DH) pre-scaled by QSCALE, K (B,H,S,DH), Vt (B,H,DH,S), bias add.
__global__ __launch_bounds__(256) void k_gemm_qkv(const short* __restrict__ A, const short* __restrict__ Bt,
                                                  const float* __restrict__ bias,
                                                  short* __restrict__ Qb, short* __restrict__ Kb,
                                                  short* __restrict__ Vt) {
  __shared__ short lA[128 * 32];
  __shared__ short lB[128 * 32];
  f32x4 acc[4][4];
#pragma unroll
  for (int m = 0; m < 4; ++m)
#pragma unroll
    for (int n = 0; n < 4; ++n)
      acc[m][n] = (f32x4){0.f, 0.f, 0.f, 0.f};
  const int row0 = blockIdx.x * 128, col0 = blockIdx.y * 128;
  gemm_core(A, Bt, row0, col0, D_, lA, lB, acc);
  const int lane = threadIdx.x & 63, wave = threadIdx.x >> 6;
  const int wr = wave >> 1, wc = wave & 1;
#pragma unroll
  for (int m = 0; m < 4; ++m) {
    const int rbase = row0 + wr * 64 + m * 16 + (lane >> 4) * 4;
#pragma unroll
    for (int n = 0; n < 4; ++n) {
      const int col = col0 + wc * 64 + n * 16 + (lane & 15);
      const float bv = bias[col];
      const int t = col >> 10, rem = col & 1023, hh = rem >> 6, e = rem & 63;
#pragma unroll
      for (int r = 0; r < 4; ++r) {
        const int rw = rbase + r;
        const int bb = rw >> 11, s = rw & 2047;
        float v = acc[m][n][r] + bv;
        if (t == 0) {
          Qb[((size_t)(bb * H_ + hh) * S_ + s) * DH_ + e] = f2bf(v * QSCALE);
        } else if (t == 1) {
          Kb[((size_t)(bb * H_ + hh) * S_ + s) * DH_ + e] = f2bf(v);
        } else {
          Vt[((size_t)(bb * H_ + hh) * DH_ + e) * S_ + s] = f2bf(v);
        }
      }
    }
  }
}

// Output GEMM: A = att (8192x1024), Bt = woutT (1024x1024), C = out f32 + bias.
__global__ __launch_bounds__(256) void k_gemm_out(const short* __restrict__ A, const short* __restrict__ Bt,
                                                  const float* __restrict__ bias, float* __restrict__ C) {
  __shared__ short lA[128 * 32];
  __shared__ short lB[128 * 32];
  f32x4 acc[4][4];
#pragma unroll
  for (int m = 0; m < 4; ++m)
#pragma unroll
    for (int n = 0; n < 4; ++n)
      acc[m][n] = (f32x4){0.f, 0.f, 0.f, 0.f};
  const int row0 = blockIdx.x * 128, col0 = blockIdx.y * 128;
  gemm_core(A, Bt, row0, col0, HDH, lA, lB, acc);
  const int lane = threadIdx.x & 63, wave = threadIdx.x >> 6;
  const int wr = wave >> 1, wc = wave & 1;
#pragma unroll
  for (int m = 0; m < 4; ++m) {
    const int rbase = row0 + wr * 64 + m * 16 + (lane >> 4) * 4;
#pragma unroll
    for (int n = 0; n < 4; ++n) {
      const int col = col0 + wc * 64 + n * 16 + (lane & 15);
      const float bv = bias[col];
#pragma unroll
      for (int r = 0; r < 4; ++r)
        C[(size_t)(rbase + r) * D_ + col] = acc[m][n][r] + bv;
    }
  }
}

// ---------------- flash attention (causal, swapped-QK^T, LDS-free) ----------------
// One wave = 32 q-rows. Swapped S^T = mfma(K, Q): lane holds 16 scores of row
// q = lane&31 at keys (r&3)+8*(r>>2)+4*hi (m74/m101 C/D map). Softmax is
// lane-local + one shfl_xor(32). P repacked to PV B-fragments via
// cvt_pk_bf16 + partner exchange (m214-verified pairing). O^T = V^T * P^T so
// the 1/l divisor is lane-local. Defer-max (T13) skips O-rescale most tiles.

template <bool MASKED>
__device__ __forceinline__ void attn_tile(int kt, int ql, int hi,
                                          const short* __restrict__ Kp,
                                          const short* __restrict__ Vp,
                                          const bf16x8 qf[4],
                                          f32x16& oacc0, f32x16& oacc1,
                                          float& m, float& lsum) {
  // ---- QK^T (swapped): A = K tile, B = Q ----
  const short* kb = Kp + (size_t)(kt + ql) * DH_ + hi * 8;
  bf16x8 kf0 = *(const bf16x8*)(kb);
  bf16x8 kf1 = *(const bf16x8*)(kb + 16);
  bf16x8 kf2 = *(const bf16x8*)(kb + 32);
  bf16x8 kf3 = *(const bf16x8*)(kb + 48);
  f32x16 sacc;
#pragma unroll
  for (int r = 0; r < 16; ++r) sacc[r] = 0.f;
  sacc = __builtin_amdgcn_mfma_f32_32x32x16_bf16(kf0, qf[0], sacc, 0, 0, 0);
  sacc = __builtin_amdgcn_mfma_f32_32x32x16_bf16(kf1, qf[1], sacc, 0, 0, 0);
  sacc = __builtin_amdgcn_mfma_f32_32x32x16_bf16(kf2, qf[2], sacc, 0, 0, 0);
  sacc = __builtin_amdgcn_mfma_f32_32x32x16_bf16(kf3, qf[3], sacc, 0, 0, 0);

  // ---- V loads early (A-operand of O^T MFMA), latency hides under softmax ----
  const short* vb0 = Vp + (size_t)(ql) * S_ + kt + hi * 8;
  const short* vb1 = Vp + (size_t)(32 + ql) * S_ + kt + hi * 8;
  bf16x8 vf00 = *(const bf16x8*)(vb0);
  bf16x8 vf01 = *(const bf16x8*)(vb0 + 16);
  bf16x8 vf10 = *(const bf16x8*)(vb1);
  bf16x8 vf11 = *(const bf16x8*)(vb1 + 16);

  // ---- mask + online softmax (log2 domain; scale pre-folded into Q) ----
  float p[16];
#pragma unroll
  for (int r = 0; r < 16; ++r) {
    float s = sacc[r];
    if (MASKED) {
      const int kl = (r & 3) + 8 * (r >> 2) + 4 * hi;
      s = (kl <= ql) ? s : -1.0e30f;
    }
    p[r] = s;
  }
  float pmax = p[0];
#pragma unroll
  for (int r = 1; r < 16; ++r) pmax = fmaxf(pmax, p[r]);
  pmax = fmaxf(pmax, __shfl_xor(pmax, 32));
  if (__any(pmax - m > 8.0f)) {           // T13 defer-max
    const float mn = fmaxf(m, pmax);
    const float al = __builtin_amdgcn_exp2f(m - mn);
    lsum *= al;
#pragma unroll
    for (int r = 0; r < 16; ++r) { oacc0[r] *= al; oacc1[r] *= al; }
    m = mn;
  }
  float psum = 0.f;
#pragma unroll
  for (int r = 0; r < 16; ++r) {
    p[r] = __builtin_amdgcn_exp2f(p[r] - m);
    psum += p[r];
  }
  lsum += psum + __shfl_xor(psum, 32);

  // ---- pack P -> two B-fragments (keys kt..kt+15, kt+16..kt+31) ----
  uint32_t A0 = cvt_pk_bf16(p[0],  p[1]);
  uint32_t A1 = cvt_pk_bf16(p[2],  p[3]);
  uint32_t B0 = cvt_pk_bf16(p[4],  p[5]);
  uint32_t B1 = cvt_pk_bf16(p[6],  p[7]);
  uint32_t A2 = cvt_pk_bf16(p[8],  p[9]);
  uint32_t A3 = cvt_pk_bf16(p[10], p[11]);
  uint32_t B2 = cvt_pk_bf16(p[12], p[13]);
  uint32_t B3 = cvt_pk_bf16(p[14], p[15]);
  uint32_t A0x = __shfl_xor(A0, 32), B0x = __shfl_xor(B0, 32);
  uint32_t A1x = __shfl_xor(A1, 32), B1x = __shfl_xor(B1, 32);
  uint32_t A2x = __shfl_xor(A2, 32), B2x = __shfl_xor(B2, 32);
  uint32_t A3x = __shfl_xor(A3, 32), B3x = __shfl_xor(B3, 32);
  union { uint32_t u[4]; bf16x8 v; } pb0, pb1;
  pb0.u[0] = hi ? B0x : A0;
  pb0.u[1] = hi ? B1x : A1;
  pb0.u[2] = hi ? B0  : A0x;
  pb0.u[3] = hi ? B1  : A1x;
  pb1.u[0] = hi ? B2x : A2;
  pb1.u[1] = hi ? B3x : A3;
  pb1.u[2] = hi ? B2  : A2x;
  pb1.u[3] = hi ? B3  : A3x;

  // ---- O^T += V^T * P^T ----
  oacc0 = __builtin_amdgcn_mfma_f32_32x32x16_bf16(vf00, pb0.v, oacc0, 0, 0, 0);
  oacc0 = __builtin_amdgcn_mfma_f32_32x32x16_bf16(vf01, pb1.v, oacc0, 0, 0, 0);
  oacc1 = __builtin_amdgcn_mfma_f32_32x32x16_bf16(vf10, pb0.v, oacc1, 0, 0, 0);
  oacc1 = __builtin_amdgcn_mfma_f32_32x32x16_bf16(vf11, pb1.v, oacc1, 0, 0, 0);
}

// grid (8, H, B) x 256 threads (4 waves). Wave w handles q-block pair
// (pi, 63-pi), pi = blockIdx.x*4 + w -> uniform 2080 keys of work per wave.
__global__ __launch_bounds__(256) void k_attn(const short* __restrict__ Qb, const short* __restrict__ Kb,
                                              const short* __restrict__ Vt, short* __restrict__ att) {
  const int wave = threadIdx.x >> 6, lane = threadIdx.x & 63;
  const int h = blockIdx.y, b = blockIdx.z;
  const int pi = blockIdx.x * 4 + wave;        // 0..31
  const size_t bh = (size_t)(b * H_ + h);
  const short* Qp = Qb + bh * (S_ * DH_);
  const short* Kp = Kb + bh * (S_ * DH_);
  const short* Vp = Vt + bh * (DH_ * S_);
  const int ql = lane & 31, hi = lane >> 5;

#pragma unroll 1
  for (int rep = 0; rep < 2; ++rep) {
    const int q0 = rep ? (S_ - 32 - pi * 32) : (pi * 32);

    bf16x8 qf[4];
#pragma unroll
    for (int s = 0; s < 4; ++s)
      qf[s] = *(const bf16x8*)(Qp + (size_t)(q0 + ql) * DH_ + s * 16 + hi * 8);

    f32x16 oacc0, oacc1;
#pragma unroll
    for (int r = 0; r < 16; ++r) { oacc0[r] = 0.f; oacc1[r] = 0.f; }
    float m = -3.0e38f, lsum = 0.f;

#pragma unroll 1
    for (int kt = 0; kt < q0; kt += 32)
      attn_tile<false>(kt, ql, hi, Kp, Vp, qf, oacc0, oacc1, m, lsum);
    attn_tile<true>(q0, ql, hi, Kp, Vp, qf, oacc0, oacc1, m, lsum);

    const float rl = __builtin_amdgcn_rcpf(lsum);
    short* ob = att + (size_t)((size_t)b * S_ + q0 + ql) * HDH + h * DH_ + 4 * hi;
#pragma unroll
    for (int dt = 0; dt < 2; ++dt) {
#pragma unroll
      for (int a = 0; a < 4; ++a) {
        const int rbase = 4 * a;
        float v0 = (dt ? oacc1[rbase + 0] : oacc0[rbase + 0]) * rl;
        float v1 = (dt ? oacc1[rbase + 1] : oacc0[rbase + 1]) * rl;
        float v2 = (dt ? oacc1[rbase + 2] : oacc0[rbase + 2]) * rl;
        float v3 = (dt ? oacc1[rbase + 3] : oacc0[rbase + 3]) * rl;
        short4 o;
        o.x = f2bf(v0); o.y = f2bf(v1); o.z = f2bf(v2); o.w = f2bf(v3);
        *(short4*)(ob + dt * 32 + 8 * a) = o;
      }
    }
  }
}

// ---------------- launcher ----------------

extern "C" void kernel_launch(void* const* d_in, const int* in_sizes, int n_in,
                              void* d_out, int out_size, void* d_ws, size_t ws_size,
                              hipStream_t stream) {
  const float* x     = (const float*)d_in[0];
  const float* w_qkv = (const float*)d_in[1];
  const float* b_qkv = (const float*)d_in[2];
  const float* w_out = (const float*)d_in[3];
  const float* b_out = (const float*)d_in[4];
  float* out = (float*)d_out;

  char* p = (char*)d_ws;
  short* xb    = (short*)p; p += (size_t)M_TOT * D_ * 2;
  short* wqkvT = (short*)p; p += (size_t)NQKV * D_ * 2;
  short* woutT = (short*)p; p += (size_t)D_ * HDH * 2;
  short* Qb    = (short*)p; p += (size_t)B_ * H_ * S_ * DH_ * 2;
  short* Kb    = (short*)p; p += (size_t)B_ * H_ * S_ * DH_ * 2;
  short* Vt    = (short*)p; p += (size_t)B_ * H_ * S_ * DH_ * 2;
  short* att   = (short*)p; p += (size_t)M_TOT * HDH * 2;

  k_cvt<<<M_TOT * D_ / 4 / 256, 256, 0, stream>>>(x, xb, M_TOT * D_ / 4);
  k_transpose<<<(D_ * NQKV + 255) / 256, 256, 0, stream>>>(w_qkv, wqkvT, D_, NQKV);
  k_transpose<<<(HDH * D_ + 255) / 256, 256, 0, stream>>>(w_out, woutT, HDH, D_);
  k_gemm_qkv<<<dim3(M_TOT / 128, NQKV / 128), 256, 0, stream>>>(xb, wqkvT, b_qkv, Qb, Kb, Vt);
  k_attn<<<dim3(8, H_, B_), 256, 0, stream>>>(Qb, Kb, Vt, att);
  k_gemm_out<<<dim3(M_TOT / 128, D_ / 128), 256, 0, stream>>>(att, woutT, b_out, out);
}

// Round 4
// 261.140 us; speedup vs baseline: 2.2409x; 1.0032x over previous
//
#include <hip/hip_runtime.h>
#include <hip/hip_bf16.h>
#include <stdint.h>

#define B_    4
#define S_    2048
#define D_    1024
#define H_    16
#define DH_   64
#define M_TOT 8192      // B*S
#define NQKV  3072      // 3*H*DH
#define HDH   1024      // H*DH

typedef __bf16 bf16_t;
typedef bf16_t bf16x8 __attribute__((ext_vector_type(8)));
typedef float  f32x4  __attribute__((ext_vector_type(4)));
typedef float  f32x16 __attribute__((ext_vector_type(16)));

// scale folded into Q at QKV epilogue: 1/sqrt(64) * log2(e)
#define QSCALE 0.1803368801111204f

__device__ __forceinline__ short f2bf(float f) {
  union { float f; uint32_t u; } x; x.f = f;
  uint32_t r = (x.u + 0x7fffu + ((x.u >> 16) & 1u)) >> 16;
  return (short)(uint16_t)r;
}

__device__ __forceinline__ uint32_t cvt_pk_bf16(float lo, float hi) {
  uint32_t r;
  asm("v_cvt_pk_bf16_f32 %0, %1, %2" : "=v"(r) : "v"(lo), "v"(hi));
  return r;
}

#define ASYNC_COPY16(g, l) \
  __builtin_amdgcn_global_load_lds((const __attribute__((address_space(1))) void*)(g), \
                                   (__attribute__((address_space(3))) void*)(l), 16, 0, 0)

// ---------------- prep kernels ----------------

__global__ __launch_bounds__(256) void k_cvt(const float* __restrict__ in, short* __restrict__ out, int n4) {
  int i = blockIdx.x * 256 + threadIdx.x;
  if (i < n4) {
    float4 v = ((const float4*)in)[i];
    short4 o;
    o.x = f2bf(v.x); o.y = f2bf(v.y); o.z = f2bf(v.z); o.w = f2bf(v.w);
    ((short4*)out)[i] = o;
  }
}

// in: (R,C) f32 row-major -> out: (C,R) bf16 row-major
__global__ __launch_bounds__(256) void k_transpose(const float* __restrict__ in, short* __restrict__ out, int R, int C) {
  int idx = blockIdx.x * 256 + threadIdx.x;
  if (idx < R * C) {
    int r = idx / C, c = idx % C;
    out[(size_t)c * R + r] = f2bf(in[idx]);
  }
}

// ---------------- GEMM core: C = A(row-major MxK) * Bt(row-major NxK)^T ----------------

__device__ __forceinline__ void gemm_core(const short* __restrict__ A,
                                          const short* __restrict__ Bt,
                                          int row0, int col0, int K,
                                          short* lA, short* lB,
                                          f32x4 acc[4][4]) {
  const int tid  = threadIdx.x;
  const int wave = tid >> 6, lane = tid & 63;
  const int wr = wave >> 1, wc = wave & 1;
  const int stg_r = lane >> 2;         // 0..15
  const int stg_k = (lane & 3) * 8;    // 0,8,16,24
  const int fr = lane & 15;
  const int fk = (lane >> 4) * 8;

  for (int k0 = 0; k0 < K; k0 += 32) {
    __syncthreads();
#pragma unroll
    for (int c = 0; c < 2; ++c) {
      const int seg = wave * 2 + c;    // 0..7
      const short* ga = A  + (size_t)(row0 + seg * 16 + stg_r) * K + (k0 + stg_k);
      const short* gb = Bt + (size_t)(col0 + seg * 16 + stg_r) * K + (k0 + stg_k);
      ASYNC_COPY16(ga, lA + seg * 512);
      ASYNC_COPY16(gb, lB + seg * 512);
    }
    __syncthreads();
    bf16x8 af[4], bfr[4];
#pragma unroll
    for (int m = 0; m < 4; ++m)
      af[m] = *(const bf16x8*)(lA + (wr * 64 + m * 16 + fr) * 32 + fk);
#pragma unroll
    for (int n = 0; n < 4; ++n)
      bfr[n] = *(const bf16x8*)(lB + (wc * 64 + n * 16 + fr) * 32 + fk);
#pragma unroll
    for (int m = 0; m < 4; ++m)
#pragma unroll
      for (int n = 0; n < 4; ++n)
        acc[m][n] = __builtin_amdgcn_mfma_f32_16x16x32_bf16(af[m], bfr[n], acc[m][n], 0, 0, 0);
  }
}

// QKV GEMM: A = x_bf16 (8192x1024), Bt = wqkvT (3072x1024). Epilogue scatters
// to Q (B,H,S,DH) pre-scaled by QSCALE, K (B,H,S,DH), Vt (B,H,DH,S), bias add.
__global__ __launch_bounds__(256) void k_gemm_qkv(const short* __restrict__ A, const short* __restrict__ Bt,
                                                  const float* __restrict__ bias,
                                                  short* __restrict__ Qb, short* __restrict__ Kb,
                                                  short* __restrict__ Vt) {
  __shared__ short lA[128 * 32];
  __shared__ short lB[128 * 32];
  f32x4 acc[4][4];
#pragma unroll
  for (int m = 0; m < 4; ++m)
#pragma unroll
    for (int n = 0; n < 4; ++n)
      acc[m][n] = (f32x4){0.f, 0.f, 0.f, 0.f};
  const int row0 = blockIdx.x * 128, col0 = blockIdx.y * 128;
  gemm_core(A, Bt, row0, col0, D_, lA, lB, acc);
  const int lane = threadIdx.x & 63, wave = threadIdx.x >> 6;
  const int wr = wave >> 1, wc = wave & 1;
#pragma unroll
  for (int m = 0; m < 4; ++m) {
    const int rbase = row0 + wr * 64 + m * 16 + (lane >> 4) * 4;
#pragma unroll
    for (int n = 0; n < 4; ++n) {
      const int col = col0 + wc * 64 + n * 16 + (lane & 15);
      const float bv = bias[col];
      const int t = col >> 10, rem = col & 1023, hh = rem >> 6, e = rem & 63;
#pragma unroll
      for (int r = 0; r < 4; ++r) {
        const int rw = rbase + r;
        const int bb = rw >> 11, s = rw & 2047;
        float v = acc[m][n][r] + bv;
        if (t == 0) {
          Qb[((size_t)(bb * H_ + hh) * S_ + s) * DH_ + e] = f2bf(v * QSCALE);
        } else if (t == 1) {
          Kb[((size_t)(bb * H_ + hh) * S_ + s) * DH_ + e] = f2bf(v);
        } else {
          Vt[((size_t)(bb * H_ + hh) * DH_ + e) * S_ + s] = f2bf(v);
        }
      }
    }
  }
}

// Output GEMM: A = att (8192x1024), Bt = woutT (1024x1024), C = out f32 + bias.
__global__ __launch_bounds__(256) void k_gemm_out(const short* __restrict__ A, const short* __restrict__ Bt,
                                                  const float* __restrict__ bias, float* __restrict__ C) {
  __shared__ short lA[128 * 32];
  __shared__ short lB[128 * 32];
  f32x4 acc[4][4];
#pragma unroll
  for (int m = 0; m < 4; ++m)
#pragma unroll
    for (int n = 0; n < 4; ++n)
      acc[m][n] = (f32x4){0.f, 0.f, 0.f, 0.f};
  const int row0 = blockIdx.x * 128, col0 = blockIdx.y * 128;
  gemm_core(A, Bt, row0, col0, HDH, lA, lB, acc);
  const int lane = threadIdx.x & 63, wave = threadIdx.x >> 6;
  const int wr = wave >> 1, wc = wave & 1;
#pragma unroll
  for (int m = 0; m < 4; ++m) {
    const int rbase = row0 + wr * 64 + m * 16 + (lane >> 4) * 4;
#pragma unroll
    for (int n = 0; n < 4; ++n) {
      const int col = col0 + wc * 64 + n * 16 + (lane & 15);
      const float bv = bias[col];
#pragma unroll
      for (int r = 0; r < 4; ++r)
        C[(size_t)(rbase + r) * D_ + col] = acc[m][n][r] + bv;
    }
  }
}

// ---------------- flash attention (causal, swapped-QK^T, LDS-free) ----------------
// Round-2-proven internals. One wave = 32 q-rows of ONE q-block. Swapped
// S^T = mfma(K, Q): lane holds 16 scores of row q = lane&31 at keys
// (r&3)+8*(r>>2)+4*hi. Softmax lane-local + one shfl_xor(32). P repacked to
// PV B-fragments via cvt_pk_bf16 + partner exchange. O^T = V^T * P^T.

template <bool MASKED>
__device__ __forceinline__ void attn_tile(int kt, int ql, int hi,
                                          const short* __restrict__ Kp,
                                          const short* __restrict__ Vp,
                                          const bf16x8 qf[4],
                                          f32x16& oacc0, f32x16& oacc1,
                                          float& m, float& lsum) {
  // ---- QK^T (swapped): A = K tile, B = Q ----
  const short* kb = Kp + (size_t)(kt + ql) * DH_ + hi * 8;
  bf16x8 kf0 = *(const bf16x8*)(kb);
  bf16x8 kf1 = *(const bf16x8*)(kb + 16);
  bf16x8 kf2 = *(const bf16x8*)(kb + 32);
  bf16x8 kf3 = *(const bf16x8*)(kb + 48);
  f32x16 sacc;
#pragma unroll
  for (int r = 0; r < 16; ++r) sacc[r] = 0.f;
  sacc = __builtin_amdgcn_mfma_f32_32x32x16_bf16(kf0, qf[0], sacc, 0, 0, 0);
  sacc = __builtin_amdgcn_mfma_f32_32x32x16_bf16(kf1, qf[1], sacc, 0, 0, 0);
  sacc = __builtin_amdgcn_mfma_f32_32x32x16_bf16(kf2, qf[2], sacc, 0, 0, 0);
  sacc = __builtin_amdgcn_mfma_f32_32x32x16_bf16(kf3, qf[3], sacc, 0, 0, 0);

  // ---- V loads early (A-operand of O^T MFMA), latency hides under softmax ----
  const short* vb0 = Vp + (size_t)(ql) * S_ + kt + hi * 8;
  const short* vb1 = Vp + (size_t)(32 + ql) * S_ + kt + hi * 8;
  bf16x8 vf00 = *(const bf16x8*)(vb0);
  bf16x8 vf01 = *(const bf16x8*)(vb0 + 16);
  bf16x8 vf10 = *(const bf16x8*)(vb1);
  bf16x8 vf11 = *(const bf16x8*)(vb1 + 16);

  // ---- mask + online softmax (log2 domain; scale pre-folded into Q) ----
  float p[16];
#pragma unroll
  for (int r = 0; r < 16; ++r) {
    float s = sacc[r];
    if (MASKED) {
      const int kl = (r & 3) + 8 * (r >> 2) + 4 * hi;
      s = (kl <= ql) ? s : -1.0e30f;
    }
    p[r] = s;
  }
  float pmax = p[0];
#pragma unroll
  for (int r = 1; r < 16; ++r) pmax = fmaxf(pmax, p[r]);
  pmax = fmaxf(pmax, __shfl_xor(pmax, 32));
  if (__any(pmax - m > 8.0f)) {           // T13 defer-max
    const float mn = fmaxf(m, pmax);
    const float al = __builtin_amdgcn_exp2f(m - mn);
    lsum *= al;
#pragma unroll
    for (int r = 0; r < 16; ++r) { oacc0[r] *= al; oacc1[r] *= al; }
    m = mn;
  }
  float psum = 0.f;
#pragma unroll
  for (int r = 0; r < 16; ++r) {
    p[r] = __builtin_amdgcn_exp2f(p[r] - m);
    psum += p[r];
  }
  lsum += psum + __shfl_xor(psum, 32);

  // ---- pack P -> two B-fragments (keys kt..kt+15, kt+16..kt+31) ----
  uint32_t A0 = cvt_pk_bf16(p[0],  p[1]);
  uint32_t A1 = cvt_pk_bf16(p[2],  p[3]);
  uint32_t B0 = cvt_pk_bf16(p[4],  p[5]);
  uint32_t B1 = cvt_pk_bf16(p[6],  p[7]);
  uint32_t A2 = cvt_pk_bf16(p[8],  p[9]);
  uint32_t A3 = cvt_pk_bf16(p[10], p[11]);
  uint32_t B2 = cvt_pk_bf16(p[12], p[13]);
  uint32_t B3 = cvt_pk_bf16(p[14], p[15]);
  uint32_t A0x = __shfl_xor(A0, 32), B0x = __shfl_xor(B0, 32);
  uint32_t A1x = __shfl_xor(A1, 32), B1x = __shfl_xor(B1, 32);
  uint32_t A2x = __shfl_xor(A2, 32), B2x = __shfl_xor(B2, 32);
  uint32_t A3x = __shfl_xor(A3, 32), B3x = __shfl_xor(B3, 32);
  union { uint32_t u[4]; bf16x8 v; } pb0, pb1;
  pb0.u[0] = hi ? B0x : A0;
  pb0.u[1] = hi ? B1x : A1;
  pb0.u[2] = hi ? B0  : A0x;
  pb0.u[3] = hi ? B1  : A1x;
  pb1.u[0] = hi ? B2x : A2;
  pb1.u[1] = hi ? B3x : A3;
  pb1.u[2] = hi ? B2  : A2x;
  pb1.u[3] = hi ? B3  : A3x;

  // ---- O^T += V^T * P^T ----
  oacc0 = __builtin_amdgcn_mfma_f32_32x32x16_bf16(vf00, pb0.v, oacc0, 0, 0, 0);
  oacc0 = __builtin_amdgcn_mfma_f32_32x32x16_bf16(vf01, pb1.v, oacc0, 0, 0, 0);
  oacc1 = __builtin_amdgcn_mfma_f32_32x32x16_bf16(vf10, pb0.v, oacc1, 0, 0, 0);
  oacc1 = __builtin_amdgcn_mfma_f32_32x32x16_bf16(vf11, pb1.v, oacc1, 0, 0, 0);
}

// 1024 blocks x 256 threads (4 waves), one q-block per wave (4096 waves =
// 4 waves/SIMD). Block-id decode keeps all 16 blocks of one (b,h) on one XCD
// (dispatch round-robins id%8) and gives same-CU blocks the same (b,h).
// Per-block q-block set {xq, 31-xq, 32+xq, 63-xq} sums to a constant 130
// tiles; rotation by xq>>2 mixes sizes across SIMD slots.
__global__ __launch_bounds__(256, 4) void k_attn(const short* __restrict__ Qb, const short* __restrict__ Kb,
                                                 const short* __restrict__ Vt, short* __restrict__ att) {
  const int wave = threadIdx.x >> 6, lane = threadIdx.x & 63;
  const int j = blockIdx.x;
  const int xcd = j & 7, c = j >> 3;       // c in [0,128)
  const int bhLo = c & 7, xq = c >> 3;     // xq in [0,16)
  const int gg = xcd + 8 * bhLo;           // (b,h) id in [0,64)
  const int b = gg >> 4, h = gg & 15;
  const int idx = (wave + (xq >> 2)) & 3;
  const int p = (idx == 0) ? xq : (idx == 1) ? (31 - xq) : (idx == 2) ? (32 + xq) : (63 - xq);
  const int q0 = p * 32;
  const size_t bh = (size_t)(b * H_ + h);
  const short* Qp = Qb + bh * (S_ * DH_);
  const short* Kp = Kb + bh * (S_ * DH_);
  const short* Vp = Vt + bh * (DH_ * S_);
  const int ql = lane & 31, hi = lane >> 5;

  bf16x8 qf[4];
#pragma unroll
  for (int s = 0; s < 4; ++s)
    qf[s] = *(const bf16x8*)(Qp + (size_t)(q0 + ql) * DH_ + s * 16 + hi * 8);

  f32x16 oacc0, oacc1;
#pragma unroll
  for (int r = 0; r < 16; ++r) { oacc0[r] = 0.f; oacc1[r] = 0.f; }
  float m = -3.0e38f, lsum = 0.f;

#pragma unroll 1
  for (int kt = 0; kt < q0; kt += 32)
    attn_tile<false>(kt, ql, hi, Kp, Vp, qf, oacc0, oacc1, m, lsum);
  attn_tile<true>(q0, ql, hi, Kp, Vp, qf, oacc0, oacc1, m, lsum);

  const float rl = __builtin_amdgcn_rcpf(lsum);
  short* ob = att + (size_t)((size_t)b * S_ + q0 + ql) * HDH + h * DH_ + 4 * hi;
#pragma unroll
  for (int dt = 0; dt < 2; ++dt) {
#pragma unroll
    for (int a = 0; a < 4; ++a) {
      const int rbase = 4 * a;
      float v0 = (dt ? oacc1[rbase + 0] : oacc0[rbase + 0]) * rl;
      float v1 = (dt ? oacc1[rbase + 1] : oacc0[rbase + 1]) * rl;
      float v2 = (dt ? oacc1[rbase + 2] : oacc0[rbase + 2]) * rl;
      float v3 = (dt ? oacc1[rbase + 3] : oacc0[rbase + 3]) * rl;
      short4 o;
      o.x = f2bf(v0); o.y = f2bf(v1); o.z = f2bf(v2); o.w = f2bf(v3);
      *(short4*)(ob + dt * 32 + 8 * a) = o;
    }
  }
}

// ---------------- launcher ----------------

extern "C" void kernel_launch(void* const* d_in, const int* in_sizes, int n_in,
                              void* d_out, int out_size, void* d_ws, size_t ws_size,
                              hipStream_t stream) {
  const float* x     = (const float*)d_in[0];
  const float* w_qkv = (const float*)d_in[1];
  const float* b_qkv = (const float*)d_in[2];
  const float* w_out = (const float*)d_in[3];
  const float* b_out = (const float*)d_in[4];
  float* out = (float*)d_out;

  char* p = (char*)d_ws;
  short* xb    = (short*)p; p += (size_t)M_TOT * D_ * 2;
  short* wqkvT = (short*)p; p += (size_t)NQKV * D_ * 2;
  short* woutT = (short*)p; p += (size_t)D_ * HDH * 2;
  short* Qb    = (short*)p; p += (size_t)B_ * H_ * S_ * DH_ * 2;
  short* Kb    = (short*)p; p += (size_t)B_ * H_ * S_ * DH_ * 2;
  short* Vt    = (short*)p; p += (size_t)B_ * H_ * S_ * DH_ * 2;
  short* att   = (short*)p; p += (size_t)M_TOT * HDH * 2;

  k_cvt<<<M_TOT * D_ / 4 / 256, 256, 0, stream>>>(x, xb, M_TOT * D_ / 4);
  k_transpose<<<(D_ * NQKV + 255) / 256, 256, 0, stream>>>(w_qkv, wqkvT, D_, NQKV);
  k_transpose<<<(HDH * D_ + 255) / 256, 256, 0, stream>>>(w_out, woutT, HDH, D_);
  k_gemm_qkv<<<dim3(M_TOT / 128, NQKV / 128), 256, 0, stream>>>(xb, wqkvT, b_qkv, Qb, Kb, Vt);
  k_attn<<<1024, 256, 0, stream>>>(Qb, Kb, Vt, att);
  k_gemm_out<<<dim3(M_TOT / 128, D_ / 128), 256, 0, stream>>>(att, woutT, b_out, out);
}

// Round 5
// 261.028 us; speedup vs baseline: 2.2419x; 1.0004x over previous
//
#include <hip/hip_runtime.h>
#include <hip/hip_bf16.h>
#include <stdint.h>

#define B_    4
#define S_    2048
#define D_    1024
#define H_    16
#define DH_   64
#define M_TOT 8192      // B*S
#define NQKV  3072      // 3*H*DH
#define HDH   1024      // H*DH

typedef __bf16 bf16_t;
typedef bf16_t bf16x8 __attribute__((ext_vector_type(8)));
typedef float  f32x4  __attribute__((ext_vector_type(4)));
typedef float  f32x16 __attribute__((ext_vector_type(16)));

// scale folded into Q at QKV epilogue: 1/sqrt(64) * log2(e)
#define QSCALE 0.1803368801111204f

__device__ __forceinline__ short f2bf(float f) {
  union { float f; uint32_t u; } x; x.f = f;
  uint32_t r = (x.u + 0x7fffu + ((x.u >> 16) & 1u)) >> 16;
  return (short)(uint16_t)r;
}

__device__ __forceinline__ uint32_t cvt_pk_bf16(float lo, float hi) {
  uint32_t r;
  asm("v_cvt_pk_bf16_f32 %0, %1, %2" : "=v"(r) : "v"(lo), "v"(hi));
  return r;
}

// d' = {d.lo, s.lo}, s' = {d.hi, s.hi}  (swaps d's high row with s's low row)
__device__ __forceinline__ void permlane32_swap(uint32_t& d, uint32_t& s) {
  asm("v_permlane32_swap_b32 %0, %1" : "+v"(d), "+v"(s));
}

#define ASYNC_COPY16(g, l) \
  __builtin_amdgcn_global_load_lds((const __attribute__((address_space(1))) void*)(g), \
                                   (__attribute__((address_space(3))) void*)(l), 16, 0, 0)

// ---------------- prep kernels ----------------

__global__ __launch_bounds__(256) void k_cvt(const float* __restrict__ in, short* __restrict__ out, int n4) {
  int i = blockIdx.x * 256 + threadIdx.x;
  if (i < n4) {
    float4 v = ((const float4*)in)[i];
    short4 o;
    o.x = f2bf(v.x); o.y = f2bf(v.y); o.z = f2bf(v.z); o.w = f2bf(v.w);
    ((short4*)out)[i] = o;
  }
}

// in: (R,C) f32 row-major -> out: (C,R) bf16 row-major
__global__ __launch_bounds__(256) void k_transpose(const float* __restrict__ in, short* __restrict__ out, int R, int C) {
  int idx = blockIdx.x * 256 + threadIdx.x;
  if (idx < R * C) {
    int r = idx / C, c = idx % C;
    out[(size_t)c * R + r] = f2bf(in[idx]);
  }
}

// ---------------- GEMM core: C = A(row-major MxK) * Bt(row-major NxK)^T ----------------

__device__ __forceinline__ void gemm_core(const short* __restrict__ A,
                                          const short* __restrict__ Bt,
                                          int row0, int col0, int K,
                                          short* lA, short* lB,
                                          f32x4 acc[4][4]) {
  const int tid  = threadIdx.x;
  const int wave = tid >> 6, lane = tid & 63;
  const int wr = wave >> 1, wc = wave & 1;
  const int stg_r = lane >> 2;         // 0..15
  const int stg_k = (lane & 3) * 8;    // 0,8,16,24
  const int fr = lane & 15;
  const int fk = (lane >> 4) * 8;

  for (int k0 = 0; k0 < K; k0 += 32) {
    __syncthreads();
#pragma unroll
    for (int c = 0; c < 2; ++c) {
      const int seg = wave * 2 + c;    // 0..7
      const short* ga = A  + (size_t)(row0 + seg * 16 + stg_r) * K + (k0 + stg_k);
      const short* gb = Bt + (size_t)(col0 + seg * 16 + stg_r) * K + (k0 + stg_k);
      ASYNC_COPY16(ga, lA + seg * 512);
      ASYNC_COPY16(gb, lB + seg * 512);
    }
    __syncthreads();
    bf16x8 af[4], bfr[4];
#pragma unroll
    for (int m = 0; m < 4; ++m)
      af[m] = *(const bf16x8*)(lA + (wr * 64 + m * 16 + fr) * 32 + fk);
#pragma unroll
    for (int n = 0; n < 4; ++n)
      bfr[n] = *(const bf16x8*)(lB + (wc * 64 + n * 16 + fr) * 32 + fk);
#pragma unroll
    for (int m = 0; m < 4; ++m)
#pragma unroll
      for (int n = 0; n < 4; ++n)
        acc[m][n] = __builtin_amdgcn_mfma_f32_16x16x32_bf16(af[m], bfr[n], acc[m][n], 0, 0, 0);
  }
}

// QKV GEMM: A = x_bf16 (8192x1024), Bt = wqkvT (3072x1024). Epilogue scatters
// to Q (B,H,S,DH) pre-scaled by QSCALE, K (B,H,S,DH), Vt (B,H,DH,S), bias add.
__global__ __launch_bounds__(256) void k_gemm_qkv(const short* __restrict__ A, const short* __restrict__ Bt,
                                                  const float* __restrict__ bias,
                                                  short* __restrict__ Qb, short* __restrict__ Kb,
                                                  short* __restrict__ Vt) {
  __shared__ short lA[128 * 32];
  __shared__ short lB[128 * 32];
  f32x4 acc[4][4];
#pragma unroll
  for (int m = 0; m < 4; ++m)
#pragma unroll
    for (int n = 0; n < 4; ++n)
      acc[m][n] = (f32x4){0.f, 0.f, 0.f, 0.f};
  const int row0 = blockIdx.x * 128, col0 = blockIdx.y * 128;
  gemm_core(A, Bt, row0, col0, D_, lA, lB, acc);
  const int lane = threadIdx.x & 63, wave = threadIdx.x >> 6;
  const int wr = wave >> 1, wc = wave & 1;
#pragma unroll
  for (int m = 0; m < 4; ++m) {
    const int rbase = row0 + wr * 64 + m * 16 + (lane >> 4) * 4;
#pragma unroll
    for (int n = 0; n < 4; ++n) {
      const int col = col0 + wc * 64 + n * 16 + (lane & 15);
      const float bv = bias[col];
      const int t = col >> 10, rem = col & 1023, hh = rem >> 6, e = rem & 63;
#pragma unroll
      for (int r = 0; r < 4; ++r) {
        const int rw = rbase + r;
        const int bb = rw >> 11, s = rw & 2047;
        float v = acc[m][n][r] + bv;
        if (t == 0) {
          Qb[((size_t)(bb * H_ + hh) * S_ + s) * DH_ + e] = f2bf(v * QSCALE);
        } else if (t == 1) {
          Kb[((size_t)(bb * H_ + hh) * S_ + s) * DH_ + e] = f2bf(v);
        } else {
          Vt[((size_t)(bb * H_ + hh) * DH_ + e) * S_ + s] = f2bf(v);
        }
      }
    }
  }
}

// Output GEMM: A = att (8192x1024), Bt = woutT (1024x1024), C = out f32 + bias.
__global__ __launch_bounds__(256) void k_gemm_out(const short* __restrict__ A, const short* __restrict__ Bt,
                                                  const float* __restrict__ bias, float* __restrict__ C) {
  __shared__ short lA[128 * 32];
  __shared__ short lB[128 * 32];
  f32x4 acc[4][4];
#pragma unroll
  for (int m = 0; m < 4; ++m)
#pragma unroll
    for (int n = 0; n < 4; ++n)
      acc[m][n] = (f32x4){0.f, 0.f, 0.f, 0.f};
  const int row0 = blockIdx.x * 128, col0 = blockIdx.y * 128;
  gemm_core(A, Bt, row0, col0, HDH, lA, lB, acc);
  const int lane = threadIdx.x & 63, wave = threadIdx.x >> 6;
  const int wr = wave >> 1, wc = wave & 1;
#pragma unroll
  for (int m = 0; m < 4; ++m) {
    const int rbase = row0 + wr * 64 + m * 16 + (lane >> 4) * 4;
#pragma unroll
    for (int n = 0; n < 4; ++n) {
      const int col = col0 + wc * 64 + n * 16 + (lane & 15);
      const float bv = bias[col];
#pragma unroll
      for (int r = 0; r < 4; ++r)
        C[(size_t)(rbase + r) * D_ + col] = acc[m][n][r] + bv;
    }
  }
}

// ---------------- flash attention (causal, swapped-QK^T, LDS-free) ----------------
// One wave = 32 q-rows of ONE q-block. Swapped S^T = mfma(K, Q): lane holds
// 16 scores of row q = lane&31 at keys (r&3)+8*(r>>2)+4*hi. Softmax fully
// lane-local in the common path (per-half pmax; per-half lsum merged once at
// the end; full-row max only inside the rare rescale branch). P packed to PV
// B-fragments via cvt_pk_bf16 + v_permlane32_swap (no LDS-pipe ops).
// K fragments are software-prefetched one tile ahead by the caller.

template <bool MASKED>
__device__ __forceinline__ void attn_tile(int kt, int ql, int hi,
                                          const short* __restrict__ Vp,
                                          const bf16x8 kf[4],
                                          const bf16x8 qf[4],
                                          f32x16& oacc0, f32x16& oacc1,
                                          float& m, float& lsum) {
  // ---- V loads early (needed only at PV; latency hides under softmax) ----
  const short* vb0 = Vp + (size_t)(ql) * S_ + kt + hi * 8;
  const short* vb1 = Vp + (size_t)(32 + ql) * S_ + kt + hi * 8;
  bf16x8 vf00 = *(const bf16x8*)(vb0);
  bf16x8 vf01 = *(const bf16x8*)(vb0 + 16);
  bf16x8 vf10 = *(const bf16x8*)(vb1);
  bf16x8 vf11 = *(const bf16x8*)(vb1 + 16);

  // ---- QK^T (swapped): A = K tile, B = Q ----
  f32x16 sacc;
#pragma unroll
  for (int r = 0; r < 16; ++r) sacc[r] = 0.f;
  __builtin_amdgcn_s_setprio(1);
  sacc = __builtin_amdgcn_mfma_f32_32x32x16_bf16(kf[0], qf[0], sacc, 0, 0, 0);
  sacc = __builtin_amdgcn_mfma_f32_32x32x16_bf16(kf[1], qf[1], sacc, 0, 0, 0);
  sacc = __builtin_amdgcn_mfma_f32_32x32x16_bf16(kf[2], qf[2], sacc, 0, 0, 0);
  sacc = __builtin_amdgcn_mfma_f32_32x32x16_bf16(kf[3], qf[3], sacc, 0, 0, 0);
  __builtin_amdgcn_s_setprio(0);

  // ---- mask + online softmax (log2 domain; scale pre-folded into Q) ----
  float p[16];
#pragma unroll
  for (int r = 0; r < 16; ++r) {
    float s = sacc[r];
    if (MASKED) {
      const int kl = (r & 3) + 8 * (r >> 2) + 4 * hi;
      s = (kl <= ql) ? s : -1.0e30f;
    }
    p[r] = s;
  }
  // per-half max (max3-friendly tree); full-row max only when rescaling
  float t0 = fmaxf(fmaxf(p[0], p[1]), p[2]);
  float t1 = fmaxf(fmaxf(p[3], p[4]), p[5]);
  float t2 = fmaxf(fmaxf(p[6], p[7]), p[8]);
  float t3 = fmaxf(fmaxf(p[9], p[10]), p[11]);
  float t4 = fmaxf(fmaxf(p[12], p[13]), p[14]);
  float pmax = fmaxf(fmaxf(fmaxf(t0, t1), t2), fmaxf(fmaxf(t3, t4), p[15]));
  if (__any(pmax - m > 8.0f)) {           // T13 defer-max (rare)
    const float pmr = fmaxf(pmax, __shfl_xor(pmax, 32));
    const float mn = fmaxf(m, pmr);
    const float al = __builtin_amdgcn_exp2f(m - mn);
    lsum *= al;
#pragma unroll
    for (int r = 0; r < 16; ++r) { oacc0[r] *= al; oacc1[r] *= al; }
    m = mn;
  }
#pragma unroll
  for (int r = 0; r < 16; ++r) p[r] = __builtin_amdgcn_exp2f(p[r] - m);
  // pairwise sum tree; per-half partial (merged once at epilogue)
  {
    float s0 = (p[0] + p[1]) + (p[2] + p[3]);
    float s1 = (p[4] + p[5]) + (p[6] + p[7]);
    float s2 = (p[8] + p[9]) + (p[10] + p[11]);
    float s3 = (p[12] + p[13]) + (p[14] + p[15]);
    lsum += (s0 + s1) + (s2 + s3);
  }

  // ---- pack P -> two B-fragments via permlane32_swap ----
  uint32_t A0 = cvt_pk_bf16(p[0],  p[1]);
  uint32_t A1 = cvt_pk_bf16(p[2],  p[3]);
  uint32_t B0 = cvt_pk_bf16(p[4],  p[5]);
  uint32_t B1 = cvt_pk_bf16(p[6],  p[7]);
  uint32_t A2 = cvt_pk_bf16(p[8],  p[9]);
  uint32_t A3 = cvt_pk_bf16(p[10], p[11]);
  uint32_t B2 = cvt_pk_bf16(p[12], p[13]);
  uint32_t B3 = cvt_pk_bf16(p[14], p[15]);
  permlane32_swap(A0, B0);   // A0 -> pb0.u[0], B0 -> pb0.u[2]
  permlane32_swap(A1, B1);   // A1 -> pb0.u[1], B1 -> pb0.u[3]
  permlane32_swap(A2, B2);   // A2 -> pb1.u[0], B2 -> pb1.u[2]
  permlane32_swap(A3, B3);   // A3 -> pb1.u[1], B3 -> pb1.u[3]
  union { uint32_t u[4]; bf16x8 v; } pb0, pb1;
  pb0.u[0] = A0; pb0.u[1] = A1; pb0.u[2] = B0; pb0.u[3] = B1;
  pb1.u[0] = A2; pb1.u[1] = A3; pb1.u[2] = B2; pb1.u[3] = B3;

  // ---- O^T += V^T * P^T ----
  __builtin_amdgcn_s_setprio(1);
  oacc0 = __builtin_amdgcn_mfma_f32_32x32x16_bf16(vf00, pb0.v, oacc0, 0, 0, 0);
  oacc0 = __builtin_amdgcn_mfma_f32_32x32x16_bf16(vf01, pb1.v, oacc0, 0, 0, 0);
  oacc1 = __builtin_amdgcn_mfma_f32_32x32x16_bf16(vf10, pb0.v, oacc1, 0, 0, 0);
  oacc1 = __builtin_amdgcn_mfma_f32_32x32x16_bf16(vf11, pb1.v, oacc1, 0, 0, 0);
  __builtin_amdgcn_s_setprio(0);
}

// 1024 blocks x 256 threads (4 waves), one q-block per wave (4096 waves).
// Block-id decode keeps all 16 blocks of one (b,h) on one XCD (dispatch
// round-robins id%8). Per-block q-block set {xq, 31-xq, 32+xq, 63-xq} sums
// to a constant 130 tiles; rotation by xq>>2 mixes sizes across SIMD slots.
__global__ __launch_bounds__(256, 4) void k_attn(const short* __restrict__ Qb, const short* __restrict__ Kb,
                                                 const short* __restrict__ Vt, short* __restrict__ att) {
  const int wave = threadIdx.x >> 6, lane = threadIdx.x & 63;
  const int j = blockIdx.x;
  const int xcd = j & 7, c = j >> 3;       // c in [0,128)
  const int bhLo = c & 7, xq = c >> 3;     // xq in [0,16)
  const int gg = xcd + 8 * bhLo;           // (b,h) id in [0,64)
  const int b = gg >> 4, h = gg & 15;
  const int idx = (wave + (xq >> 2)) & 3;
  const int p = (idx == 0) ? xq : (idx == 1) ? (31 - xq) : (idx == 2) ? (32 + xq) : (63 - xq);
  const int q0 = p * 32;
  const size_t bh = (size_t)(b * H_ + h);
  const short* Qp = Qb + bh * (S_ * DH_);
  const short* Kp = Kb + bh * (S_ * DH_);
  const short* Vp = Vt + bh * (DH_ * S_);
  const int ql = lane & 31, hi = lane >> 5;

  bf16x8 qf[4];
#pragma unroll
  for (int s = 0; s < 4; ++s)
    qf[s] = *(const bf16x8*)(Qp + (size_t)(q0 + ql) * DH_ + s * 16 + hi * 8);

  f32x16 oacc0, oacc1;
#pragma unroll
  for (int r = 0; r < 16; ++r) { oacc0[r] = 0.f; oacc1[r] = 0.f; }
  float m = -3.0e38f, lsum = 0.f;

  // K fragments for tile 0 (prologue), then prefetch one tile ahead.
  const short* kb0 = Kp + (size_t)(ql) * DH_ + hi * 8;
  bf16x8 kcur[4];
  kcur[0] = *(const bf16x8*)(kb0);
  kcur[1] = *(const bf16x8*)(kb0 + 16);
  kcur[2] = *(const bf16x8*)(kb0 + 32);
  kcur[3] = *(const bf16x8*)(kb0 + 48);

#pragma unroll 1
  for (int kt = 0; kt < q0; kt += 32) {
    // prefetch K for tile kt+32 (always valid: kt+32 <= q0 = diagonal tile)
    const short* kbn = Kp + (size_t)(kt + 32 + ql) * DH_ + hi * 8;
    bf16x8 knext[4];
    knext[0] = *(const bf16x8*)(kbn);
    knext[1] = *(const bf16x8*)(kbn + 16);
    knext[2] = *(const bf16x8*)(kbn + 32);
    knext[3] = *(const bf16x8*)(kbn + 48);
    attn_tile<false>(kt, ql, hi, Vp, kcur, qf, oacc0, oacc1, m, lsum);
    kcur[0] = knext[0]; kcur[1] = knext[1]; kcur[2] = knext[2]; kcur[3] = knext[3];
  }
  attn_tile<true>(q0, ql, hi, Vp, kcur, qf, oacc0, oacc1, m, lsum);

  lsum += __shfl_xor(lsum, 32);            // merge per-half partials (once)
  const float rl = __builtin_amdgcn_rcpf(lsum);
  short* ob = att + (size_t)((size_t)b * S_ + q0 + ql) * HDH + h * DH_ + 4 * hi;
#pragma unroll
  for (int dt = 0; dt < 2; ++dt) {
#pragma unroll
    for (int a = 0; a < 4; ++a) {
      const int rbase = 4 * a;
      float v0 = (dt ? oacc1[rbase + 0] : oacc0[rbase + 0]) * rl;
      float v1 = (dt ? oacc1[rbase + 1] : oacc0[rbase + 1]) * rl;
      float v2 = (dt ? oacc1[rbase + 2] : oacc0[rbase + 2]) * rl;
      float v3 = (dt ? oacc1[rbase + 3] : oacc0[rbase + 3]) * rl;
      short4 o;
      o.x = f2bf(v0); o.y = f2bf(v1); o.z = f2bf(v2); o.w = f2bf(v3);
      *(short4*)(ob + dt * 32 + 8 * a) = o;
    }
  }
}

// ---------------- launcher ----------------

extern "C" void kernel_launch(void* const* d_in, const int* in_sizes, int n_in,
                              void* d_out, int out_size, void* d_ws, size_t ws_size,
                              hipStream_t stream) {
  const float* x     = (const float*)d_in[0];
  const float* w_qkv = (const float*)d_in[1];
  const float* b_qkv = (const float*)d_in[2];
  const float* w_out = (const float*)d_in[3];
  const float* b_out = (const float*)d_in[4];
  float* out = (float*)d_out;

  char* p = (char*)d_ws;
  short* xb    = (short*)p; p += (size_t)M_TOT * D_ * 2;
  short* wqkvT = (short*)p; p += (size_t)NQKV * D_ * 2;
  short* woutT = (short*)p; p += (size_t)D_ * HDH * 2;
  short* Qb    = (short*)p; p += (size_t)B_ * H_ * S_ * DH_ * 2;
  short* Kb    = (short*)p; p += (size_t)B_ * H_ * S_ * DH_ * 2;
  short* Vt    = (short*)p; p += (size_t)B_ * H_ * S_ * DH_ * 2;
  short* att   = (short*)p; p += (size_t)M_TOT * HDH * 2;

  k_cvt<<<M_TOT * D_ / 4 / 256, 256, 0, stream>>>(x, xb, M_TOT * D_ / 4);
  k_transpose<<<(D_ * NQKV + 255) / 256, 256, 0, stream>>>(w_qkv, wqkvT, D_, NQKV);
  k_transpose<<<(HDH * D_ + 255) / 256, 256, 0, stream>>>(w_out, woutT, HDH, D_);
  k_gemm_qkv<<<dim3(M_TOT / 128, NQKV / 128), 256, 0, stream>>>(xb, wqkvT, b_qkv, Qb, Kb, Vt);
  k_attn<<<1024, 256, 0, stream>>>(Qb, Kb, Vt, att);
  k_gemm_out<<<dim3(M_TOT / 128, D_ / 128), 256, 0, stream>>>(att, woutT, b_out, out);
}